// Round 2
// baseline (409.643 us; speedup 1.0000x reference)
//
#include <hip/hip_runtime.h>

#define NBATCH 16384
#define NAG 32
#define DOBS 64
#define DH 64
#define DA 16
#define LSTRIDE 72   // shorts per staged h row: 64 + 8 pad (keeps 16B alignment, spreads banks)
#define WSLOT 2432   // shorts per wave slot: 32*72 = 2304 (h) + 64 (S) + 64 pad

typedef __attribute__((ext_vector_type(8))) short bf16x8;
typedef __attribute__((ext_vector_type(4))) float f32x4;

__device__ __forceinline__ short f2bf(float f) {        // truncate (activations; threshold is huge)
  return (short)(__float_as_uint(f) >> 16);
}
__device__ __forceinline__ short f2bf_rne(float f) {    // RNE (weights, done once)
  unsigned u = __float_as_uint(f);
  return (short)((u + 0x7fffu + ((u >> 16) & 1u)) >> 16);
}

// ---------------------------------------------------------------------------
// Setup: pack all weights into per-lane MFMA B-fragment layout in d_ws (bf16).
//   f 0..7   : enc_w            f 8..23 : W_eff[r]=Wtop-Wbot/31
//   f 24..39 : V[r]=Wbot/31     f 40..47: out_w1      f 48..49: out_w2
// ---------------------------------------------------------------------------
__global__ void build_frags(const float* __restrict__ enc_w, const float* __restrict__ comm_w,
                            const float* __restrict__ out_w1, const float* __restrict__ out_w2,
                            short* __restrict__ wf) {
  int e = blockIdx.x * blockDim.x + threadIdx.x;
  if (e >= 50 * 512) return;
  int f = e >> 9;
  int lane = (e >> 3) & 63;
  int j = e & 7;
  int quad = lane >> 4, col = lane & 15;
  float val;
  if (f < 8) {
    int kk = (f >> 2) & 1, nn = f & 3;
    int k = kk * 32 + quad * 8 + j, n = nn * 16 + col;
    val = enc_w[k * DH + n];
  } else if (f < 24) {
    int g = f - 8; int r = g >> 3, kk = (g >> 2) & 1, nn = g & 3;
    int k = kk * 32 + quad * 8 + j, n = nn * 16 + col;
    const float* W = comm_w + r * (2 * DH * DH);
    val = W[k * DH + n] - W[(DH + k) * DH + n] * (1.0f / 31.0f);
  } else if (f < 40) {
    int g = f - 24; int r = g >> 3, kk = (g >> 2) & 1, nn = g & 3;
    int k = kk * 32 + quad * 8 + j, n = nn * 16 + col;
    const float* W = comm_w + r * (2 * DH * DH);
    val = W[(DH + k) * DH + n] * (1.0f / 31.0f);
  } else if (f < 48) {
    int g = f - 40; int kk = (g >> 2) & 1, nn = g & 3;
    int k = kk * 32 + quad * 8 + j, n = nn * 16 + col;
    val = out_w1[k * DH + n];
  } else {
    int kk = f - 48;
    int k = kk * 32 + quad * 8 + j;
    val = out_w2[k * DA + col];
  }
  wf[e] = f2bf_rne(val);
}

// ---------------------------------------------------------------------------
template<bool WITH_T, bool WITH_S>
__device__ __forceinline__ void stage_h(const f32x4 (&acc)[2][4], const float (&t)[4],
                                        short* hb, short* sb, int quad, int col) {
#pragma unroll
  for (int nn = 0; nn < 4; nn++) {
    float s = 0.f;
#pragma unroll
    for (int m2 = 0; m2 < 2; m2++) {
#pragma unroll
      for (int r = 0; r < 4; r++) {
        float v = acc[m2][nn][r];
        if constexpr (WITH_T) v += t[nn];
        v = fmaxf(v, 0.f);
        hb[(m2 * 16 + quad * 4 + r) * LSTRIDE + nn * 16 + col] = f2bf(v);
        if constexpr (WITH_S) s += v;
      }
    }
    if constexpr (WITH_S) {
      s += __shfl_xor(s, 16, 64);
      s += __shfl_xor(s, 32, 64);
      sb[nn * 16 + col] = f2bf(s);
    }
  }
}

__device__ __forceinline__ void read_afrags(bf16x8 (&ah)[2][2], const short* hb, int quad, int col) {
#pragma unroll
  for (int m2 = 0; m2 < 2; m2++)
#pragma unroll
    for (int kk = 0; kk < 2; kk++)
      ah[m2][kk] = *(const bf16x8*)(hb + (m2 * 16 + col) * LSTRIDE + kk * 32 + quad * 8);
}

__device__ __forceinline__ void read_sfrags(bf16x8 (&as)[2], const short* sb, int quad, int col) {
  const bf16x8 z = {0, 0, 0, 0, 0, 0, 0, 0};
#pragma unroll
  for (int kk = 0; kk < 2; kk++) {
    bf16x8 v = *(const bf16x8*)(sb + kk * 32 + quad * 8);
    as[kk] = (col == 0) ? v : z;   // S occupies row 0 of the extra M-tile
  }
}

// issue global loads for one batch's obs (8 x 16B per lane, coalesced)
__device__ __forceinline__ void issue_obs(const float* __restrict__ obs, int b,
                                          int quad, int col, f32x4 (&pf)[8]) {
#pragma unroll
  for (int m2 = 0; m2 < 2; m2++)
#pragma unroll
    for (int kk = 0; kk < 2; kk++) {
      const float* p = obs + ((b * NAG + m2 * 16 + col) * DOBS + kk * 32 + quad * 8);
      pf[(m2 * 2 + kk) * 2 + 0] = *(const f32x4*)p;
      pf[(m2 * 2 + kk) * 2 + 1] = *(const f32x4*)(p + 4);
    }
}

__device__ __forceinline__ void issue_avail(const int* __restrict__ avail, int b,
                                            int quad, int col, int (&pav)[8]) {
#pragma unroll
  for (int m2 = 0; m2 < 2; m2++)
#pragma unroll
    for (int r = 0; r < 4; r++) {
      int row = m2 * 16 + quad * 4 + r;
      pav[m2 * 4 + r] = avail[(b * NAG + row) * DA + col];
    }
}

__global__ void __launch_bounds__(256, 3) commnet_main(
    const float* __restrict__ obs,
    const float* __restrict__ enc_b,
    const float* __restrict__ comm_b,
    const float* __restrict__ out_b1,
    const float* __restrict__ out_b2,
    const int* __restrict__ avail,
    const short* __restrict__ wf_raw,
    float* __restrict__ out) {
  __shared__ short hbuf[4 * WSLOT];
  const int tid = threadIdx.x;
  const int wave = tid >> 6;
  const int lane = tid & 63;
  const int quad = lane >> 4, col = lane & 15;
  short* hb = hbuf + wave * WSLOT;
  short* sb = hb + 2304;
  const bf16x8* wf = (const bf16x8*)wf_raw;

  int b = blockIdx.x * 4 + wave;
  const int wstep = 4096;           // gridDim(1024) * 4 waves; exactly 4 iterations

  // prefetch batch 0 of this wave (obs + avail) before anything else
  f32x4 pf[8];
  int pav[8];
  issue_obs(obs, b, quad, col, pf);
  issue_avail(avail, b, quad, col, pav);

  // biases (L2-hot broadcast loads), kept in registers for the whole kernel
  float eb[4], cbb[2][4], ob1[4];
#pragma unroll
  for (int nn = 0; nn < 4; nn++) {
    eb[nn] = enc_b[nn * 16 + col];
    cbb[0][nn] = comm_b[nn * 16 + col];
    cbb[1][nn] = comm_b[DH + nn * 16 + col];
    ob1[nn] = out_b1[nn * 16 + col];
  }
  float ob2 = out_b2[col];

#pragma unroll 1
  for (int it = 0; it < 4; it++) {
    const int bn = (it < 3) ? (b + wstep) : 0;   // last iter: dummy prefetch of batch 0 (L2-hot)

    // ---- convert prefetched obs f32 -> bf16 A-frags, then re-issue pf for bn ----
    bf16x8 aob[2][2];
#pragma unroll
    for (int m2 = 0; m2 < 2; m2++)
#pragma unroll
      for (int kk = 0; kk < 2; kk++) {
        f32x4 x0 = pf[(m2 * 2 + kk) * 2 + 0];
        f32x4 x1 = pf[(m2 * 2 + kk) * 2 + 1];
        bf16x8 a;
        a[0] = f2bf(x0[0]); a[1] = f2bf(x0[1]); a[2] = f2bf(x0[2]); a[3] = f2bf(x0[3]);
        a[4] = f2bf(x1[0]); a[5] = f2bf(x1[1]); a[6] = f2bf(x1[2]); a[7] = f2bf(x1[3]);
        aob[m2][kk] = a;
      }
    issue_obs(obs, bn, quad, col, pf);   // in flight across the whole batch body

    // ---------------- GEMM1: h0 = relu(obs @ enc_w + enc_b) ----------------
    f32x4 acc[2][4];
#pragma unroll
    for (int nn = 0; nn < 4; nn++) {
      f32x4 c; c[0] = c[1] = c[2] = c[3] = eb[nn];
      acc[0][nn] = c; acc[1][nn] = c;
    }
#pragma unroll
    for (int kk = 0; kk < 2; kk++) {
#pragma unroll
      for (int nn = 0; nn < 4; nn++) {
        bf16x8 w = wf[(kk * 4 + nn) * 64 + lane];
        acc[0][nn] = __builtin_amdgcn_mfma_f32_16x16x32_bf16(aob[0][kk], w, acc[0][nn], 0, 0, 0);
        acc[1][nn] = __builtin_amdgcn_mfma_f32_16x16x32_bf16(aob[1][kk], w, acc[1][nn], 0, 0, 0);
      }
    }
    float tz[4] = {0.f, 0.f, 0.f, 0.f};
    stage_h<false, true>(acc, tz, hb, sb, quad, col);
    bf16x8 ah[2][2]; read_afrags(ah, hb, quad, col);
    bf16x8 as[2];    read_sfrags(as, sb, quad, col);

    // ------------- comm rounds: h = relu(h@W_eff + S@V + b) ---------------
    // aS computed FIRST so its 16 accumulator VGPRs die before a2's 32 are live.
#pragma unroll
    for (int r = 0; r < 2; r++) {
      f32x4 aS[4];
#pragma unroll
      for (int nn = 0; nn < 4; nn++) { f32x4 z; z[0] = z[1] = z[2] = z[3] = 0.f; aS[nn] = z; }
#pragma unroll
      for (int kk = 0; kk < 2; kk++)
#pragma unroll
        for (int nn = 0; nn < 4; nn++) {
          bf16x8 vv = wf[(24 + r * 8 + kk * 4 + nn) * 64 + lane];
          aS[nn] = __builtin_amdgcn_mfma_f32_16x16x32_bf16(as[kk], vv, aS[nn], 0, 0, 0);
        }
      float t[4];
#pragma unroll
      for (int nn = 0; nn < 4; nn++) t[nn] = __shfl(aS[nn][0], col, 64);  // row 0 of S-tile

      f32x4 a2[2][4];
#pragma unroll
      for (int nn = 0; nn < 4; nn++) {
        f32x4 c; c[0] = c[1] = c[2] = c[3] = cbb[r][nn];
        a2[0][nn] = c; a2[1][nn] = c;
      }
#pragma unroll
      for (int kk = 0; kk < 2; kk++)
#pragma unroll
        for (int nn = 0; nn < 4; nn++) {
          bf16x8 we = wf[(8 + r * 8 + kk * 4 + nn) * 64 + lane];
          a2[0][nn] = __builtin_amdgcn_mfma_f32_16x16x32_bf16(ah[0][kk], we, a2[0][nn], 0, 0, 0);
          a2[1][nn] = __builtin_amdgcn_mfma_f32_16x16x32_bf16(ah[1][kk], we, a2[1][nn], 0, 0, 0);
        }
      if (r == 0) {
        stage_h<true, true>(a2, t, hb, sb, quad, col);
        read_afrags(ah, hb, quad, col);
        read_sfrags(as, sb, quad, col);
      } else {
        stage_h<true, false>(a2, t, hb, sb, quad, col);
        read_afrags(ah, hb, quad, col);
      }
    }

    // ---------------- out1: hid = relu(h @ out_w1 + out_b1) ---------------
    f32x4 a3[2][4];
#pragma unroll
    for (int nn = 0; nn < 4; nn++) {
      f32x4 c; c[0] = c[1] = c[2] = c[3] = ob1[nn];
      a3[0][nn] = c; a3[1][nn] = c;
    }
#pragma unroll
    for (int kk = 0; kk < 2; kk++)
#pragma unroll
      for (int nn = 0; nn < 4; nn++) {
        bf16x8 w = wf[(40 + kk * 4 + nn) * 64 + lane];
        a3[0][nn] = __builtin_amdgcn_mfma_f32_16x16x32_bf16(ah[0][kk], w, a3[0][nn], 0, 0, 0);
        a3[1][nn] = __builtin_amdgcn_mfma_f32_16x16x32_bf16(ah[1][kk], w, a3[1][nn], 0, 0, 0);
      }
    stage_h<false, false>(a3, tz, hb, sb, quad, col);
    read_afrags(ah, hb, quad, col);

    // ---------------- out2 + mask + store ---------------------------------
    f32x4 a4[2];
    {
      f32x4 c; c[0] = c[1] = c[2] = c[3] = ob2;
      a4[0] = c; a4[1] = c;
    }
#pragma unroll
    for (int kk = 0; kk < 2; kk++) {
      bf16x8 w = wf[(48 + kk) * 64 + lane];
      a4[0] = __builtin_amdgcn_mfma_f32_16x16x32_bf16(ah[0][kk], w, a4[0], 0, 0, 0);
      a4[1] = __builtin_amdgcn_mfma_f32_16x16x32_bf16(ah[1][kk], w, a4[1], 0, 0, 0);
    }
#pragma unroll
    for (int m2 = 0; m2 < 2; m2++) {
#pragma unroll
      for (int r = 0; r < 4; r++) {
        int row = m2 * 16 + quad * 4 + r;
        int idx = (b * NAG + row) * DA + col;
        float q = a4[m2][r];
        out[idx] = (pav[m2 * 4 + r] == 0) ? -1e10f : q;
      }
    }
    // avail prefetch for next batch AFTER the stores so pav regs can be reused (WAR clear)
    issue_avail(avail, bn, quad, col, pav);

    b += wstep;
  }
}

extern "C" void kernel_launch(void* const* d_in, const int* in_sizes, int n_in,
                              void* d_out, int out_size, void* d_ws, size_t ws_size,
                              hipStream_t stream) {
  const float* obs    = (const float*)d_in[0];
  const float* enc_w  = (const float*)d_in[1];
  const float* enc_b  = (const float*)d_in[2];
  const float* comm_w = (const float*)d_in[3];
  const float* comm_b = (const float*)d_in[4];
  const float* out_b1 = (const float*)d_in[5];
  const float* out_b2 = (const float*)d_in[7];
  const float* out_b1_ = (const float*)d_in[6];
  const float* out_w2 = (const float*)d_in[7];
  const float* out_b2_ = (const float*)d_in[8];
  const int*   avail  = (const int*)d_in[9];
  const float* out_w1 = (const float*)d_in[5];
  short* wf = (short*)d_ws;  // 50 frags * 512 bf16 = 51200 B of scratch

  build_frags<<<100, 256, 0, stream>>>(enc_w, comm_w, out_w1, out_w2, wf);
  commnet_main<<<1024, 256, 0, stream>>>(obs, enc_b, comm_b, out_b1_, out_b2_, avail, wf,
                                         (float*)d_out);
}

// Round 3
// 308.158 us; speedup vs baseline: 1.3293x; 1.3293x over previous
//
#include <hip/hip_runtime.h>

#define NBATCH 16384
#define NAG 32
#define DOBS 64
#define DH 64
#define DA 16
#define LSTRIDE 72   // shorts per staged h row: 64 + 8 pad (keeps 16B alignment, spreads banks)
#define WSLOT 2432   // shorts per wave slot: 32*72 = 2304 (h) + 64 (S) + 64 pad

typedef __attribute__((ext_vector_type(8))) short bf16x8;
typedef __attribute__((ext_vector_type(4))) float f32x4;

__device__ __forceinline__ short f2bf(float f) {        // truncate (activations; threshold is huge)
  return (short)(__float_as_uint(f) >> 16);
}
__device__ __forceinline__ short f2bf_rne(float f) {    // RNE (weights, done once)
  unsigned u = __float_as_uint(f);
  return (short)((u + 0x7fffu + ((u >> 16) & 1u)) >> 16);
}

// ---------------------------------------------------------------------------
// Setup: pack all weights into per-lane MFMA B-fragment layout in d_ws (bf16).
//   f 0..7   : enc_w            f 8..23 : W_eff[r]=Wtop-Wbot/31
//   f 24..39 : V[r]=Wbot/31     f 40..47: out_w1      f 48..49: out_w2
// ---------------------------------------------------------------------------
__global__ void build_frags(const float* __restrict__ enc_w, const float* __restrict__ comm_w,
                            const float* __restrict__ out_w1, const float* __restrict__ out_w2,
                            short* __restrict__ wf) {
  int e = blockIdx.x * blockDim.x + threadIdx.x;
  if (e >= 50 * 512) return;
  int f = e >> 9;
  int lane = (e >> 3) & 63;
  int j = e & 7;
  int quad = lane >> 4, col = lane & 15;
  float val;
  if (f < 8) {
    int kk = (f >> 2) & 1, nn = f & 3;
    int k = kk * 32 + quad * 8 + j, n = nn * 16 + col;
    val = enc_w[k * DH + n];
  } else if (f < 24) {
    int g = f - 8; int r = g >> 3, kk = (g >> 2) & 1, nn = g & 3;
    int k = kk * 32 + quad * 8 + j, n = nn * 16 + col;
    const float* W = comm_w + r * (2 * DH * DH);
    val = W[k * DH + n] - W[(DH + k) * DH + n] * (1.0f / 31.0f);
  } else if (f < 40) {
    int g = f - 24; int r = g >> 3, kk = (g >> 2) & 1, nn = g & 3;
    int k = kk * 32 + quad * 8 + j, n = nn * 16 + col;
    const float* W = comm_w + r * (2 * DH * DH);
    val = W[(DH + k) * DH + n] * (1.0f / 31.0f);
  } else if (f < 48) {
    int g = f - 40; int kk = (g >> 2) & 1, nn = g & 3;
    int k = kk * 32 + quad * 8 + j, n = nn * 16 + col;
    val = out_w1[k * DH + n];
  } else {
    int kk = f - 48;
    int k = kk * 32 + quad * 8 + j;
    val = out_w2[k * DA + col];
  }
  wf[e] = f2bf_rne(val);
}

// ---------------------------------------------------------------------------
template<bool WITH_T, bool WITH_S>
__device__ __forceinline__ void stage_h(const f32x4 (&acc)[2][4], const float (&t)[4],
                                        short* hb, short* sb, int quad, int col) {
#pragma unroll
  for (int nn = 0; nn < 4; nn++) {
    float s = 0.f;
#pragma unroll
    for (int m2 = 0; m2 < 2; m2++) {
#pragma unroll
      for (int r = 0; r < 4; r++) {
        float v = acc[m2][nn][r];
        if constexpr (WITH_T) v += t[nn];
        v = fmaxf(v, 0.f);
        hb[(m2 * 16 + quad * 4 + r) * LSTRIDE + nn * 16 + col] = f2bf(v);
        if constexpr (WITH_S) s += v;
      }
    }
    if constexpr (WITH_S) {
      s += __shfl_xor(s, 16, 64);
      s += __shfl_xor(s, 32, 64);
      sb[nn * 16 + col] = f2bf(s);
    }
  }
}

__device__ __forceinline__ void read_afrags(bf16x8 (&ah)[2][2], const short* hb, int quad, int col) {
#pragma unroll
  for (int m2 = 0; m2 < 2; m2++)
#pragma unroll
    for (int kk = 0; kk < 2; kk++)
      ah[m2][kk] = *(const bf16x8*)(hb + (m2 * 16 + col) * LSTRIDE + kk * 32 + quad * 8);
}

__device__ __forceinline__ void read_sfrags(bf16x8 (&as)[2], const short* sb, int quad, int col) {
  const bf16x8 z = {0, 0, 0, 0, 0, 0, 0, 0};
#pragma unroll
  for (int kk = 0; kk < 2; kk++) {
    bf16x8 v = *(const bf16x8*)(sb + kk * 32 + quad * 8);
    as[kk] = (col == 0) ? v : z;   // S occupies row 0 of the extra M-tile
  }
}

// issue global loads for one batch's obs (8 x 16B per lane, coalesced)
__device__ __forceinline__ void issue_obs(const float* __restrict__ obs, int b,
                                          int quad, int col, f32x4 (&pf)[8]) {
#pragma unroll
  for (int m2 = 0; m2 < 2; m2++)
#pragma unroll
    for (int kk = 0; kk < 2; kk++) {
      const float* p = obs + ((b * NAG + m2 * 16 + col) * DOBS + kk * 32 + quad * 8);
      pf[(m2 * 2 + kk) * 2 + 0] = *(const f32x4*)p;
      pf[(m2 * 2 + kk) * 2 + 1] = *(const f32x4*)(p + 4);
    }
}

__device__ __forceinline__ void issue_avail(const int* __restrict__ avail, int b,
                                            int quad, int col, int (&pav)[8]) {
#pragma unroll
  for (int m2 = 0; m2 < 2; m2++)
#pragma unroll
    for (int r = 0; r < 4; r++) {
      int row = m2 * 16 + quad * 4 + r;
      pav[m2 * 4 + r] = avail[(b * NAG + row) * DA + col];
    }
}

// launch_bounds(256,2): 256-VGPR cap. (256,3) in R2 capped at ~170 and the
// compiler spilled the 40-reg prefetch window to scratch (+340 MB HBM, 1.6x slower).
__global__ void __launch_bounds__(256, 2) commnet_main(
    const float* __restrict__ obs,
    const float* __restrict__ enc_b,
    const float* __restrict__ comm_b,
    const float* __restrict__ out_b1,
    const float* __restrict__ out_b2,
    const int* __restrict__ avail,
    const short* __restrict__ wf_raw,
    float* __restrict__ out) {
  __shared__ short hbuf[4 * WSLOT];
  const int tid = threadIdx.x;
  const int wave = tid >> 6;
  const int lane = tid & 63;
  const int quad = lane >> 4, col = lane & 15;
  short* hb = hbuf + wave * WSLOT;
  short* sb = hb + 2304;
  const bf16x8* wf = (const bf16x8*)wf_raw;

  int b = blockIdx.x * 4 + wave;
  const int wstep = 4096;           // gridDim(1024) * 4 waves; exactly 4 iterations

  // prefetch batch 0 of this wave (obs + avail) before anything else
  f32x4 pf[8];
  int pav[8];
  issue_obs(obs, b, quad, col, pf);
  issue_avail(avail, b, quad, col, pav);

  // biases (L2-hot broadcast loads), kept in registers for the whole kernel
  float eb[4], cbb[2][4], ob1[4];
#pragma unroll
  for (int nn = 0; nn < 4; nn++) {
    eb[nn] = enc_b[nn * 16 + col];
    cbb[0][nn] = comm_b[nn * 16 + col];
    cbb[1][nn] = comm_b[DH + nn * 16 + col];
    ob1[nn] = out_b1[nn * 16 + col];
  }
  float ob2 = out_b2[col];

#pragma unroll 1
  for (int it = 0; it < 4; it++) {
    const int bn = (it < 3) ? (b + wstep) : 0;   // last iter: dummy prefetch of batch 0 (L2-hot)

    // ---- convert prefetched obs f32 -> bf16 A-frags, then re-issue pf for bn ----
    bf16x8 aob[2][2];
#pragma unroll
    for (int m2 = 0; m2 < 2; m2++)
#pragma unroll
      for (int kk = 0; kk < 2; kk++) {
        f32x4 x0 = pf[(m2 * 2 + kk) * 2 + 0];
        f32x4 x1 = pf[(m2 * 2 + kk) * 2 + 1];
        bf16x8 a;
        a[0] = f2bf(x0[0]); a[1] = f2bf(x0[1]); a[2] = f2bf(x0[2]); a[3] = f2bf(x0[3]);
        a[4] = f2bf(x1[0]); a[5] = f2bf(x1[1]); a[6] = f2bf(x1[2]); a[7] = f2bf(x1[3]);
        aob[m2][kk] = a;
      }
    issue_obs(obs, bn, quad, col, pf);   // in flight across the whole batch body

    // ---------------- GEMM1: h0 = relu(obs @ enc_w + enc_b) ----------------
    f32x4 acc[2][4];
#pragma unroll
    for (int nn = 0; nn < 4; nn++) {
      f32x4 c; c[0] = c[1] = c[2] = c[3] = eb[nn];
      acc[0][nn] = c; acc[1][nn] = c;
    }
#pragma unroll
    for (int kk = 0; kk < 2; kk++) {
#pragma unroll
      for (int nn = 0; nn < 4; nn++) {
        bf16x8 w = wf[(kk * 4 + nn) * 64 + lane];
        acc[0][nn] = __builtin_amdgcn_mfma_f32_16x16x32_bf16(aob[0][kk], w, acc[0][nn], 0, 0, 0);
        acc[1][nn] = __builtin_amdgcn_mfma_f32_16x16x32_bf16(aob[1][kk], w, acc[1][nn], 0, 0, 0);
      }
    }
    float tz[4] = {0.f, 0.f, 0.f, 0.f};
    stage_h<false, true>(acc, tz, hb, sb, quad, col);
    bf16x8 ah[2][2]; read_afrags(ah, hb, quad, col);
    bf16x8 as[2];    read_sfrags(as, sb, quad, col);

    // ------------- comm rounds: h = relu(h@W_eff + S@V + b) ---------------
    // aS computed FIRST so its 16 accumulator VGPRs die before a2's 32 are live.
#pragma unroll
    for (int r = 0; r < 2; r++) {
      f32x4 aS[4];
#pragma unroll
      for (int nn = 0; nn < 4; nn++) { f32x4 z; z[0] = z[1] = z[2] = z[3] = 0.f; aS[nn] = z; }
#pragma unroll
      for (int kk = 0; kk < 2; kk++)
#pragma unroll
        for (int nn = 0; nn < 4; nn++) {
          bf16x8 vv = wf[(24 + r * 8 + kk * 4 + nn) * 64 + lane];
          aS[nn] = __builtin_amdgcn_mfma_f32_16x16x32_bf16(as[kk], vv, aS[nn], 0, 0, 0);
        }
      float t[4];
#pragma unroll
      for (int nn = 0; nn < 4; nn++) t[nn] = __shfl(aS[nn][0], col, 64);  // row 0 of S-tile

      f32x4 a2[2][4];
#pragma unroll
      for (int nn = 0; nn < 4; nn++) {
        f32x4 c; c[0] = c[1] = c[2] = c[3] = cbb[r][nn];
        a2[0][nn] = c; a2[1][nn] = c;
      }
#pragma unroll
      for (int kk = 0; kk < 2; kk++)
#pragma unroll
        for (int nn = 0; nn < 4; nn++) {
          bf16x8 we = wf[(8 + r * 8 + kk * 4 + nn) * 64 + lane];
          a2[0][nn] = __builtin_amdgcn_mfma_f32_16x16x32_bf16(ah[0][kk], we, a2[0][nn], 0, 0, 0);
          a2[1][nn] = __builtin_amdgcn_mfma_f32_16x16x32_bf16(ah[1][kk], we, a2[1][nn], 0, 0, 0);
        }
      if (r == 0) {
        stage_h<true, true>(a2, t, hb, sb, quad, col);
        read_afrags(ah, hb, quad, col);
        read_sfrags(as, sb, quad, col);
      } else {
        stage_h<true, false>(a2, t, hb, sb, quad, col);
        read_afrags(ah, hb, quad, col);
      }
    }

    // ---------------- out1: hid = relu(h @ out_w1 + out_b1) ---------------
    f32x4 a3[2][4];
#pragma unroll
    for (int nn = 0; nn < 4; nn++) {
      f32x4 c; c[0] = c[1] = c[2] = c[3] = ob1[nn];
      a3[0][nn] = c; a3[1][nn] = c;
    }
#pragma unroll
    for (int kk = 0; kk < 2; kk++)
#pragma unroll
      for (int nn = 0; nn < 4; nn++) {
        bf16x8 w = wf[(40 + kk * 4 + nn) * 64 + lane];
        a3[0][nn] = __builtin_amdgcn_mfma_f32_16x16x32_bf16(ah[0][kk], w, a3[0][nn], 0, 0, 0);
        a3[1][nn] = __builtin_amdgcn_mfma_f32_16x16x32_bf16(ah[1][kk], w, a3[1][nn], 0, 0, 0);
      }
    stage_h<false, false>(a3, tz, hb, sb, quad, col);
    read_afrags(ah, hb, quad, col);

    // ---------------- out2 + mask + store ---------------------------------
    f32x4 a4[2];
    {
      f32x4 c; c[0] = c[1] = c[2] = c[3] = ob2;
      a4[0] = c; a4[1] = c;
    }
#pragma unroll
    for (int kk = 0; kk < 2; kk++) {
      bf16x8 w = wf[(48 + kk) * 64 + lane];
      a4[0] = __builtin_amdgcn_mfma_f32_16x16x32_bf16(ah[0][kk], w, a4[0], 0, 0, 0);
      a4[1] = __builtin_amdgcn_mfma_f32_16x16x32_bf16(ah[1][kk], w, a4[1], 0, 0, 0);
    }
#pragma unroll
    for (int m2 = 0; m2 < 2; m2++) {
#pragma unroll
      for (int r = 0; r < 4; r++) {
        int row = m2 * 16 + quad * 4 + r;
        int idx = (b * NAG + row) * DA + col;
        float q = a4[m2][r];
        out[idx] = (pav[m2 * 4 + r] == 0) ? -1e10f : q;
      }
    }
    // avail prefetch for next batch AFTER the stores so pav regs can be reused (WAR clear)
    issue_avail(avail, bn, quad, col, pav);

    b += wstep;
  }
}

extern "C" void kernel_launch(void* const* d_in, const int* in_sizes, int n_in,
                              void* d_out, int out_size, void* d_ws, size_t ws_size,
                              hipStream_t stream) {
  const float* obs    = (const float*)d_in[0];
  const float* enc_w  = (const float*)d_in[1];
  const float* enc_b  = (const float*)d_in[2];
  const float* comm_w = (const float*)d_in[3];
  const float* comm_b = (const float*)d_in[4];
  const float* out_w1 = (const float*)d_in[5];
  const float* out_b1 = (const float*)d_in[6];
  const float* out_w2 = (const float*)d_in[7];
  const float* out_b2 = (const float*)d_in[8];
  const int*   avail  = (const int*)d_in[9];
  short* wf = (short*)d_ws;  // 50 frags * 512 bf16 = 51200 B of scratch

  build_frags<<<100, 256, 0, stream>>>(enc_w, comm_w, out_w1, out_w2, wf);
  commnet_main<<<1024, 256, 0, stream>>>(obs, enc_b, comm_b, out_b1, out_b2, avail, wf,
                                         (float*)d_out);
}

// Round 4
// 246.779 us; speedup vs baseline: 1.6600x; 1.2487x over previous
//
#include <hip/hip_runtime.h>

#define NBATCH 16384
#define NAG 32
#define DOBS 64
#define DH 64
#define DA 16
#define LSTRIDE 72   // shorts per staged h row: 64 + 8 pad (keeps 16B alignment, spreads banks)
#define WSLOT 2432   // shorts per wave slot: 32*72 = 2304 (h) + 64 (S) + 64 pad
#define NLDSF 42     // frags 8..49 staged in LDS (enc_w's 8 stay in L2; 64KB/block cap)

typedef __attribute__((ext_vector_type(8))) short bf16x8;
typedef __attribute__((ext_vector_type(4))) float f32x4;

__device__ __forceinline__ short f2bf(float f) {        // truncate (activations; threshold is huge)
  return (short)(__float_as_uint(f) >> 16);
}
__device__ __forceinline__ short f2bf_rne(float f) {    // RNE (weights, done once)
  unsigned u = __float_as_uint(f);
  return (short)((u + 0x7fffu + ((u >> 16) & 1u)) >> 16);
}

// ---------------------------------------------------------------------------
// Setup: pack all weights into per-lane MFMA B-fragment layout in d_ws (bf16).
//   f 0..7   : enc_w            f 8..23 : W_eff[r]=Wtop-Wbot/31
//   f 24..39 : V[r]=Wbot/31     f 40..47: out_w1      f 48..49: out_w2
// ---------------------------------------------------------------------------
__global__ void build_frags(const float* __restrict__ enc_w, const float* __restrict__ comm_w,
                            const float* __restrict__ out_w1, const float* __restrict__ out_w2,
                            short* __restrict__ wf) {
  int e = blockIdx.x * blockDim.x + threadIdx.x;
  if (e >= 50 * 512) return;
  int f = e >> 9;
  int lane = (e >> 3) & 63;
  int j = e & 7;
  int quad = lane >> 4, col = lane & 15;
  float val;
  if (f < 8) {
    int kk = (f >> 2) & 1, nn = f & 3;
    int k = kk * 32 + quad * 8 + j, n = nn * 16 + col;
    val = enc_w[k * DH + n];
  } else if (f < 24) {
    int g = f - 8; int r = g >> 3, kk = (g >> 2) & 1, nn = g & 3;
    int k = kk * 32 + quad * 8 + j, n = nn * 16 + col;
    const float* W = comm_w + r * (2 * DH * DH);
    val = W[k * DH + n] - W[(DH + k) * DH + n] * (1.0f / 31.0f);
  } else if (f < 40) {
    int g = f - 24; int r = g >> 3, kk = (g >> 2) & 1, nn = g & 3;
    int k = kk * 32 + quad * 8 + j, n = nn * 16 + col;
    const float* W = comm_w + r * (2 * DH * DH);
    val = W[(DH + k) * DH + n] * (1.0f / 31.0f);
  } else if (f < 48) {
    int g = f - 40; int kk = (g >> 2) & 1, nn = g & 3;
    int k = kk * 32 + quad * 8 + j, n = nn * 16 + col;
    val = out_w1[k * DH + n];
  } else {
    int kk = f - 48;
    int k = kk * 32 + quad * 8 + j;
    val = out_w2[k * DA + col];
  }
  wf[e] = f2bf_rne(val);
}

// ---------------------------------------------------------------------------
template<bool WITH_T, bool WITH_S>
__device__ __forceinline__ void stage_h(const f32x4 (&acc)[2][4], const float (&t)[4],
                                        short* hb, short* sb, int quad, int col) {
#pragma unroll
  for (int nn = 0; nn < 4; nn++) {
    float s = 0.f;
#pragma unroll
    for (int m2 = 0; m2 < 2; m2++) {
#pragma unroll
      for (int r = 0; r < 4; r++) {
        float v = acc[m2][nn][r];
        if constexpr (WITH_T) v += t[nn];
        v = fmaxf(v, 0.f);
        hb[(m2 * 16 + quad * 4 + r) * LSTRIDE + nn * 16 + col] = f2bf(v);
        if constexpr (WITH_S) s += v;
      }
    }
    if constexpr (WITH_S) {
      s += __shfl_xor(s, 16, 64);
      s += __shfl_xor(s, 32, 64);
      sb[nn * 16 + col] = f2bf(s);
    }
  }
}

__device__ __forceinline__ void read_afrags(bf16x8 (&ah)[2][2], const short* hb, int quad, int col) {
#pragma unroll
  for (int m2 = 0; m2 < 2; m2++)
#pragma unroll
    for (int kk = 0; kk < 2; kk++)
      ah[m2][kk] = *(const bf16x8*)(hb + (m2 * 16 + col) * LSTRIDE + kk * 32 + quad * 8);
}

__device__ __forceinline__ void read_sfrags(bf16x8 (&as)[2], const short* sb, int quad, int col) {
  const bf16x8 z = {0, 0, 0, 0, 0, 0, 0, 0};
#pragma unroll
  for (int kk = 0; kk < 2; kk++) {
    bf16x8 v = *(const bf16x8*)(sb + kk * 32 + quad * 8);
    as[kk] = (col == 0) ? v : z;   // S occupies row 0 of the extra M-tile
  }
}

// issue global loads for one batch's obs (8 x 16B per lane, coalesced)
__device__ __forceinline__ void issue_obs(const float* __restrict__ obs, int b,
                                          int quad, int col, f32x4 (&pf)[8]) {
#pragma unroll
  for (int m2 = 0; m2 < 2; m2++)
#pragma unroll
    for (int kk = 0; kk < 2; kk++) {
      const float* p = obs + ((b * NAG + m2 * 16 + col) * DOBS + kk * 32 + quad * 8);
      pf[(m2 * 2 + kk) * 2 + 0] = *(const f32x4*)p;
      pf[(m2 * 2 + kk) * 2 + 1] = *(const f32x4*)(p + 4);
    }
}

__device__ __forceinline__ void issue_avail(const int* __restrict__ avail, int b,
                                            int quad, int col, int (&pav)[8]) {
#pragma unroll
  for (int m2 = 0; m2 < 2; m2++)
#pragma unroll
    for (int r = 0; r < 4; r++) {
      int row = m2 * 16 + quad * 4 + r;
      pav[m2 * 4 + r] = avail[(b * NAG + row) * DA + col];
    }
}

// weight frag f: 0..7 from L2 (enc_w, iteration-start, overlaps obs wait);
// 8..49 from the per-block LDS stage. f is a constant after unrolling.
__device__ __forceinline__ bf16x8 wfrag(const bf16x8* __restrict__ wf,
                                        const short* lw, int f, int lane) {
  return (f < 8) ? wf[f * 64 + lane]
                 : *(const bf16x8*)(lw + (f - 8) * 512 + lane * 8);
}

// launch_bounds(256,2): 256-VGPR cap. (256,3) in R2 capped lower and the
// compiler spilled to scratch (+340 MB HBM, 1.6x slower).
__global__ void __launch_bounds__(256, 2) commnet_main(
    const float* __restrict__ obs,
    const float* __restrict__ enc_b,
    const float* __restrict__ comm_b,
    const float* __restrict__ out_b1,
    const float* __restrict__ out_b2,
    const int* __restrict__ avail,
    const short* __restrict__ wf_raw,
    float* __restrict__ out) {
  // 42 weight frags (43008 B) + 4 wave slots (19456 B) = 62464 B < 64 KB/block
  __shared__ short lds_w[NLDSF * 512];
  __shared__ short hbuf[4 * WSLOT];
  const int tid = threadIdx.x;
  const int wave = tid >> 6;
  const int lane = tid & 63;
  const int quad = lane >> 4, col = lane & 15;
  short* hb = hbuf + wave * WSLOT;
  short* sb = hb + 2304;
  const bf16x8* wf = (const bf16x8*)wf_raw;

  // ---- one-time cooperative weight staging: L2 -> LDS (amortized over 16 batches)
  for (int f = 8 + wave; f < 50; f += 4)
    *(bf16x8*)(lds_w + (f - 8) * 512 + lane * 8) = wf[f * 64 + lane];

  int b = blockIdx.x * 4 + wave;
  const int wstep = 4096;           // gridDim(1024) * 4 waves; exactly 4 iterations

  // prefetch batch 0 of this wave (obs + avail) while staging completes
  f32x4 pf[8];
  int pav[8];
  issue_obs(obs, b, quad, col, pf);
  issue_avail(avail, b, quad, col, pav);

  // biases (L2-hot broadcast loads), kept in registers for the whole kernel
  float eb[4], cbb[2][4], ob1[4];
#pragma unroll
  for (int nn = 0; nn < 4; nn++) {
    eb[nn] = enc_b[nn * 16 + col];
    cbb[0][nn] = comm_b[nn * 16 + col];
    cbb[1][nn] = comm_b[DH + nn * 16 + col];
    ob1[nn] = out_b1[nn * 16 + col];
  }
  float ob2 = out_b2[col];

  __syncthreads();   // all waves see the fully-staged lds_w

#pragma unroll 1
  for (int it = 0; it < 4; it++) {
    const int bn = (it < 3) ? (b + wstep) : 0;   // last iter: dummy prefetch of batch 0 (L2-hot)

    // ---- convert prefetched obs f32 -> bf16 A-frags, then re-issue pf for bn ----
    bf16x8 aob[2][2];
#pragma unroll
    for (int m2 = 0; m2 < 2; m2++)
#pragma unroll
      for (int kk = 0; kk < 2; kk++) {
        f32x4 x0 = pf[(m2 * 2 + kk) * 2 + 0];
        f32x4 x1 = pf[(m2 * 2 + kk) * 2 + 1];
        bf16x8 a;
        a[0] = f2bf(x0[0]); a[1] = f2bf(x0[1]); a[2] = f2bf(x0[2]); a[3] = f2bf(x0[3]);
        a[4] = f2bf(x1[0]); a[5] = f2bf(x1[1]); a[6] = f2bf(x1[2]); a[7] = f2bf(x1[3]);
        aob[m2][kk] = a;
      }
    issue_obs(obs, bn, quad, col, pf);   // in flight across the whole batch body

    // ---------------- GEMM1: h0 = relu(obs @ enc_w + enc_b) ----------------
    f32x4 acc[2][4];
#pragma unroll
    for (int nn = 0; nn < 4; nn++) {
      f32x4 c; c[0] = c[1] = c[2] = c[3] = eb[nn];
      acc[0][nn] = c; acc[1][nn] = c;
    }
#pragma unroll
    for (int kk = 0; kk < 2; kk++) {
#pragma unroll
      for (int nn = 0; nn < 4; nn++) {
        bf16x8 w = wfrag(wf, lds_w, kk * 4 + nn, lane);
        acc[0][nn] = __builtin_amdgcn_mfma_f32_16x16x32_bf16(aob[0][kk], w, acc[0][nn], 0, 0, 0);
        acc[1][nn] = __builtin_amdgcn_mfma_f32_16x16x32_bf16(aob[1][kk], w, acc[1][nn], 0, 0, 0);
      }
    }
    float tz[4] = {0.f, 0.f, 0.f, 0.f};
    stage_h<false, true>(acc, tz, hb, sb, quad, col);
    bf16x8 ah[2][2]; read_afrags(ah, hb, quad, col);
    bf16x8 as[2];    read_sfrags(as, sb, quad, col);

    // ------------- comm rounds: h = relu(h@W_eff + S@V + b) ---------------
    // aS computed FIRST so its 16 accumulator VGPRs die before a2's 32 are live.
#pragma unroll
    for (int r = 0; r < 2; r++) {
      f32x4 aS[4];
#pragma unroll
      for (int nn = 0; nn < 4; nn++) { f32x4 z; z[0] = z[1] = z[2] = z[3] = 0.f; aS[nn] = z; }
#pragma unroll
      for (int kk = 0; kk < 2; kk++)
#pragma unroll
        for (int nn = 0; nn < 4; nn++) {
          bf16x8 vv = wfrag(wf, lds_w, 24 + r * 8 + kk * 4 + nn, lane);
          aS[nn] = __builtin_amdgcn_mfma_f32_16x16x32_bf16(as[kk], vv, aS[nn], 0, 0, 0);
        }
      float t[4];
#pragma unroll
      for (int nn = 0; nn < 4; nn++) t[nn] = __shfl(aS[nn][0], col, 64);  // row 0 of S-tile

      f32x4 a2[2][4];
#pragma unroll
      for (int nn = 0; nn < 4; nn++) {
        f32x4 c; c[0] = c[1] = c[2] = c[3] = cbb[r][nn];
        a2[0][nn] = c; a2[1][nn] = c;
      }
#pragma unroll
      for (int kk = 0; kk < 2; kk++)
#pragma unroll
        for (int nn = 0; nn < 4; nn++) {
          bf16x8 we = wfrag(wf, lds_w, 8 + r * 8 + kk * 4 + nn, lane);
          a2[0][nn] = __builtin_amdgcn_mfma_f32_16x16x32_bf16(ah[0][kk], we, a2[0][nn], 0, 0, 0);
          a2[1][nn] = __builtin_amdgcn_mfma_f32_16x16x32_bf16(ah[1][kk], we, a2[1][nn], 0, 0, 0);
        }
      if (r == 0) {
        stage_h<true, true>(a2, t, hb, sb, quad, col);
        read_afrags(ah, hb, quad, col);
        read_sfrags(as, sb, quad, col);
      } else {
        stage_h<true, false>(a2, t, hb, sb, quad, col);
        read_afrags(ah, hb, quad, col);
      }
    }

    // ---------------- out1: hid = relu(h @ out_w1 + out_b1) ---------------
    f32x4 a3[2][4];
#pragma unroll
    for (int nn = 0; nn < 4; nn++) {
      f32x4 c; c[0] = c[1] = c[2] = c[3] = ob1[nn];
      a3[0][nn] = c; a3[1][nn] = c;
    }
#pragma unroll
    for (int kk = 0; kk < 2; kk++)
#pragma unroll
      for (int nn = 0; nn < 4; nn++) {
        bf16x8 w = wfrag(wf, lds_w, 40 + kk * 4 + nn, lane);
        a3[0][nn] = __builtin_amdgcn_mfma_f32_16x16x32_bf16(ah[0][kk], w, a3[0][nn], 0, 0, 0);
        a3[1][nn] = __builtin_amdgcn_mfma_f32_16x16x32_bf16(ah[1][kk], w, a3[1][nn], 0, 0, 0);
      }
    stage_h<false, false>(a3, tz, hb, sb, quad, col);
    read_afrags(ah, hb, quad, col);

    // ---------------- out2 + mask + store ---------------------------------
    f32x4 a4[2];
    {
      f32x4 c; c[0] = c[1] = c[2] = c[3] = ob2;
      a4[0] = c; a4[1] = c;
    }
#pragma unroll
    for (int kk = 0; kk < 2; kk++) {
      bf16x8 w = wfrag(wf, lds_w, 48 + kk, lane);
      a4[0] = __builtin_amdgcn_mfma_f32_16x16x32_bf16(ah[0][kk], w, a4[0], 0, 0, 0);
      a4[1] = __builtin_amdgcn_mfma_f32_16x16x32_bf16(ah[1][kk], w, a4[1], 0, 0, 0);
    }
#pragma unroll
    for (int m2 = 0; m2 < 2; m2++) {
#pragma unroll
      for (int r = 0; r < 4; r++) {
        int row = m2 * 16 + quad * 4 + r;
        int idx = (b * NAG + row) * DA + col;
        float q = a4[m2][r];
        out[idx] = (pav[m2 * 4 + r] == 0) ? -1e10f : q;
      }
    }
    // avail prefetch for next batch AFTER the stores so pav regs can be reused (WAR clear)
    issue_avail(avail, bn, quad, col, pav);

    b += wstep;
  }
}

extern "C" void kernel_launch(void* const* d_in, const int* in_sizes, int n_in,
                              void* d_out, int out_size, void* d_ws, size_t ws_size,
                              hipStream_t stream) {
  const float* obs    = (const float*)d_in[0];
  const float* enc_w  = (const float*)d_in[1];
  const float* enc_b  = (const float*)d_in[2];
  const float* comm_w = (const float*)d_in[3];
  const float* comm_b = (const float*)d_in[4];
  const float* out_w1 = (const float*)d_in[5];
  const float* out_b1 = (const float*)d_in[6];
  const float* out_w2 = (const float*)d_in[7];
  const float* out_b2 = (const float*)d_in[8];
  const int*   avail  = (const int*)d_in[9];
  short* wf = (short*)d_ws;  // 50 frags * 512 bf16 = 51200 B of scratch

  build_frags<<<100, 256, 0, stream>>>(enc_w, comm_w, out_w1, out_w2, wf);
  commnet_main<<<1024, 256, 0, stream>>>(obs, enc_b, comm_b, out_b1, out_b2, avail, wf,
                                         (float*)d_out);
}